// Round 9
// baseline (267.794 us; speedup 1.0000x reference)
//
#include <hip/hip_runtime.h>
#include <hip/hip_cooperative_groups.h>

typedef __attribute__((ext_vector_type(8))) short bf16x8;
typedef __attribute__((ext_vector_type(16))) float f32x16;

#define LN 8192
#define SA_ROWB 4240          // bytes/shifted-copy row; 4240/16=265 ≡ 1 (mod 8) → bank spread
#define SB_OFF  33920         // B buffer starts after 8 A-rows (8*4240)
#define SMEM_BYTES 65536

__device__ __forceinline__ unsigned short f2bf(float f) {
    unsigned int u = __float_as_uint(f);
    u += 0x7fffu + ((u >> 16) & 1u);
    return (unsigned short)(u >> 16);
}
__device__ __forceinline__ float lrelu(float v) { return v > 0.f ? v : 0.01f * v; }
__device__ __forceinline__ float gldx(const float* p, int i) { return (i >= 0 && i < LN) ? p[i] : 0.f; }

// Fused: phase A = ACF via 32x32x16 bf16 MFMA (round-8 verified math) -> ws
//        grid.sync -> phase B = layer1 neuron-tiled -> h1g
//        grid.sync -> phase C = layers 2+3 row-per-block -> out
__global__ __launch_bounds__(1024)
void fused_kernel(const float* __restrict__ x,
                  const float* __restrict__ W1, const float* __restrict__ b1,
                  const float* __restrict__ W2, const float* __restrict__ b2,
                  const float* __restrict__ W3, const float* __restrict__ b3,
                  float* __restrict__ ws, float* __restrict__ h1g,
                  float* __restrict__ out)
{
    __shared__ __align__(16) unsigned char smem[SMEM_BYTES];
    __shared__ float red[16];

    const int tid  = threadIdx.x;
    const int bid  = blockIdx.x;
    const int lane = tid & 63;
    const int wv   = tid >> 6;

    // ================= phase A: ACF (round-8 verified) =================
    {
        const int row = bid;
        const float* xr = x + (size_t)row * LN;

        const int jj = lane & 31;
        const int gp = lane >> 5;
        const int dd = lane & 7;
        const int hh = (lane >> 3) & 3;
        const int aoff_lane = dd * SA_ROWB + 64 + 16 * gp - 16 * hh;

        const int q  = wv & 3;
        const int p  = wv >> 2;
        const int T1 = p;
        const int T2 = 7 - p;
        const int s2 = 64 + 64 * p;
        const int i0 = 144 * q;
        const int i1 = i0 + 144;
        const int mq0 = (i0 <= 2 * s2) ? (72 * q)       : (i0 - s2);
        const int mqE = (i1 <= 2 * s2) ? (72 * (q + 1)) : (i1 - s2);

        // stage B: padded bf16 v, 16B-slot XOR swizzle
        for (int s = tid; s < 1156; s += 1024) {
            const int e0 = s * 8;
            float4 fa, fb;
            if (e0 + 7 < LN) {
                fa = *(const float4*)(xr + e0);
                fb = *(const float4*)(xr + e0 + 4);
            } else {
                fa = make_float4(gldx(xr,e0),   gldx(xr,e0+1), gldx(xr,e0+2), gldx(xr,e0+3));
                fb = make_float4(gldx(xr,e0+4), gldx(xr,e0+5), gldx(xr,e0+6), gldx(xr,e0+7));
            }
            uint4 pk;
            pk.x = (unsigned)f2bf(fa.x) | ((unsigned)f2bf(fa.y) << 16);
            pk.y = (unsigned)f2bf(fa.z) | ((unsigned)f2bf(fa.w) << 16);
            pk.z = (unsigned)f2bf(fb.x) | ((unsigned)f2bf(fb.y) << 16);
            pk.w = (unsigned)f2bf(fb.z) | ((unsigned)f2bf(fb.w) << 16);
            const int ph = s ^ ((s >> 3) & 7);
            *(uint4*)(smem + SB_OFF + ph * 16) = pk;
        }

        f32x16 acc1 = {}, acc2 = {};

        for (int ch = 0; ch < 4; ++ch) {
            const int tc = ch << 11;
            __syncthreads();
            if (tid < 528) {
                const int base = tc + 4 * tid - 40;
                float4 fa, fb, fc;
                if (base >= 0 && base + 11 < LN) {
                    fa = *(const float4*)(xr + base);
                    fb = *(const float4*)(xr + base + 4);
                    fc = *(const float4*)(xr + base + 8);
                } else {
                    fa = make_float4(gldx(xr,base),   gldx(xr,base+1), gldx(xr,base+2),  gldx(xr,base+3));
                    fb = make_float4(gldx(xr,base+4), gldx(xr,base+5), gldx(xr,base+6),  gldx(xr,base+7));
                    fc = make_float4(gldx(xr,base+8), gldx(xr,base+9), gldx(xr,base+10), gldx(xr,base+11));
                }
                unsigned short us[12];
                us[0]=f2bf(fa.x); us[1]=f2bf(fa.y); us[2]=f2bf(fa.z);  us[3]=f2bf(fa.w);
                us[4]=f2bf(fb.x); us[5]=f2bf(fb.y); us[6]=f2bf(fb.z);  us[7]=f2bf(fb.w);
                us[8]=f2bf(fc.x); us[9]=f2bf(fc.y); us[10]=f2bf(fc.z); us[11]=f2bf(fc.w);
                #pragma unroll
                for (int d = 0; d < 8; ++d) {
                    unsigned long long pk = (unsigned long long)us[8-d]
                                          | ((unsigned long long)us[9-d]  << 16)
                                          | ((unsigned long long)us[10-d] << 32)
                                          | ((unsigned long long)us[11-d] << 48);
                    *(unsigned long long*)(smem + d * SA_ROWB + 8 * tid) = pk;
                }
            }
            __syncthreads();

            const int cb = ch * 128;
            int m0 = mq0 > cb ? mq0 : cb;
            int mE = mqE < cb + 128 ? mqE : cb + 128;
            if (m0 < mE) {
                int mD = mE < s2 ? mE : s2;
                if (mD < m0) mD = m0;
                const unsigned char* ap = smem + aoff_lane + 32 * (m0 - cb);
                int S1 = 128 * T1 + 2 * m0 + 4 * jj + gp;
                int S2 = 128 * T2 + 2 * m0 + 4 * jj + gp;
                for (int mq = m0; mq < mD; mq += 4) {
                    bf16x8 A[4], B1[4], B2[4];
                    #pragma unroll
                    for (int u = 0; u < 4; ++u) {
                        A[u] = *(const bf16x8*)(ap + 32 * u);
                        const int sa = S1 + 2 * u, sb = S2 + 2 * u;
                        B1[u] = *(const bf16x8*)(smem + SB_OFF + ((sa ^ ((sa >> 3) & 7)) << 4));
                        B2[u] = *(const bf16x8*)(smem + SB_OFF + ((sb ^ ((sb >> 3) & 7)) << 4));
                    }
                    #pragma unroll
                    for (int u = 0; u < 4; ++u) {
                        acc1 = __builtin_amdgcn_mfma_f32_32x32x16_bf16(A[u], B1[u], acc1, 0, 0, 0);
                        acc2 = __builtin_amdgcn_mfma_f32_32x32x16_bf16(A[u], B2[u], acc2, 0, 0, 0);
                    }
                    ap += 128; S1 += 8; S2 += 8;
                }
                for (int mq = mD; mq < mE; mq += 4) {
                    bf16x8 A[4], B1[4];
                    #pragma unroll
                    for (int u = 0; u < 4; ++u) {
                        A[u] = *(const bf16x8*)(ap + 32 * u);
                        const int sa = S1 + 2 * u;
                        B1[u] = *(const bf16x8*)(smem + SB_OFF + ((sa ^ ((sa >> 3) & 7)) << 4));
                    }
                    #pragma unroll
                    for (int u = 0; u < 4; ++u)
                        acc1 = __builtin_amdgcn_mfma_f32_32x32x16_bf16(A[u], B1[u], acc1, 0, 0, 0);
                    ap += 128; S1 += 8;
                }
            }
        }

        __syncthreads();

        auto pwrite = [&](int T, int s, const f32x16& acc, bool add) {
            unsigned char* bp = smem + (T * 2 + s) * 4096 + jj * 128;
            #pragma unroll
            for (int rq = 0; rq < 4; ++rq) {
                const int bi = (2 * rq + gp) ^ (jj & 7);
                float4 w = make_float4(acc[4*rq], acc[4*rq+1], acc[4*rq+2], acc[4*rq+3]);
                float4* pp = (float4*)(bp + bi * 16);
                if (add) { float4 o = *pp; w.x += o.x; w.y += o.y; w.z += o.z; w.w += o.w; }
                *pp = w;
            }
        };
        if (q < 2) { pwrite(T1, q, acc1, false); pwrite(T2, q, acc2, false); }
        __syncthreads();
        if (q >= 2) { pwrite(T1, q - 2, acc1, true); pwrite(T2, q - 2, acc2, true); }
        __syncthreads();

        {
            const int T  = tid >> 7;
            const int j2 = (tid >> 2) & 31;
            const int rq = tid & 3;
            const unsigned char* b0 = smem + (T * 2) * 4096 + j2 * 128;
            const int biA = (2 * rq)     ^ (j2 & 7);
            const int biB = (2 * rq + 1) ^ (j2 & 7);
            float4 s0a = *(const float4*)(b0 + biA * 16);
            float4 s0b = *(const float4*)(b0 + biB * 16);
            float4 s1a = *(const float4*)(b0 + 4096 + biA * 16);
            float4 s1b = *(const float4*)(b0 + 4096 + biB * 16);
            float v0 = s0a.x + s1a.x, v1 = s0a.y + s1a.y, v2 = s0a.z + s1a.z, v3 = s0a.w + s1a.w;
            float v4 = s0b.x + s1b.x, v5 = s0b.y + s1b.y, v6 = s0b.z + s1b.z, v7 = s0b.w + s1b.w;
            float m = fmaxf(fmaxf(fmaxf(v0, v1), fmaxf(v2, v3)), fmaxf(fmaxf(v4, v5), fmaxf(v6, v7)));

            float mx = m;
            for (int off = 32; off > 0; off >>= 1) mx = fmaxf(mx, __shfl_xor(mx, off));
            if (lane == 0) red[wv] = mx;
            __syncthreads();
            float pmax = red[0];
            #pragma unroll
            for (int k = 1; k < 16; ++k) pmax = fmaxf(pmax, red[k]);
            ws[(size_t)row * 1024 + tid] = m * (1.0f / pmax);
        }
    }

    __threadfence();
    cooperative_groups::this_grid().sync();

    // ================= phase B: layer 1, neuron-tiled =================
    {
        const int bn = bid & 7;
        const int rb = bid >> 3;
        float4* a4 = (float4*)smem;                      // 8 rows x 1024 = 32KB
        const float4* src = (const float4*)(ws + (size_t)rb * 8192);
        for (int i = tid; i < 2048; i += 1024) a4[i] = src[i];
        __syncthreads();

        const int n0 = bn * 64 + wv * 4;
        float acc[4][8];
        #pragma unroll
        for (int u = 0; u < 4; ++u)
            #pragma unroll
            for (int r = 0; r < 8; ++r) acc[u][r] = 0.f;

        #pragma unroll
        for (int qq = 0; qq < 4; ++qq) {
            const int kq = lane + 64 * qq;
            float4 av[8];
            #pragma unroll
            for (int r = 0; r < 8; ++r) av[r] = a4[r * 256 + kq];
            #pragma unroll
            for (int u = 0; u < 4; ++u) {
                float4 w = ((const float4*)(W1 + (size_t)(n0 + u) * 1024))[kq];
                #pragma unroll
                for (int r = 0; r < 8; ++r)
                    acc[u][r] += w.x*av[r].x + w.y*av[r].y + w.z*av[r].z + w.w*av[r].w;
            }
        }
        #pragma unroll
        for (int off = 32; off > 0; off >>= 1)
            #pragma unroll
            for (int u = 0; u < 4; ++u)
                #pragma unroll
                for (int r = 0; r < 8; ++r) acc[u][r] += __shfl_xor(acc[u][r], off);

        if (lane == 0) {
            #pragma unroll
            for (int r = 0; r < 8; ++r) {
                float4 hv;
                hv.x = lrelu(acc[0][r] + b1[n0]);
                hv.y = lrelu(acc[1][r] + b1[n0 + 1]);
                hv.z = lrelu(acc[2][r] + b1[n0 + 2]);
                hv.w = lrelu(acc[3][r] + b1[n0 + 3]);
                *(float4*)(h1g + (size_t)(rb * 8 + r) * 512 + n0) = hv;
            }
        }
    }

    __threadfence();
    cooperative_groups::this_grid().sync();

    // ================= phase C: layers 2+3, row-per-block =================
    {
        const int row = bid;
        float* h1s = (float*)smem;                       // 512 floats
        float* h2  = (float*)(smem + 2048);              // 256 floats
        if (tid < 128) ((float4*)h1s)[tid] = ((const float4*)(h1g + (size_t)row * 512))[tid];
        __syncthreads();

        {
            const float4* a4 = (const float4*)h1s;
            float4 av0 = a4[lane], av1 = a4[lane + 64];
            for (int n0 = 0; n0 < 16; n0 += 8) {
                const int nb = wv * 16 + n0;
                float s[8];
                #pragma unroll
                for (int u = 0; u < 8; ++u) {
                    const float4* wr = (const float4*)(W2 + (size_t)(nb + u) * 512);
                    float4 w0 = wr[lane], w1 = wr[lane + 64];
                    float t0 = w0.x*av0.x + w0.y*av0.y + w0.z*av0.z + w0.w*av0.w;
                    float t1 = w1.x*av1.x + w1.y*av1.y + w1.z*av1.z + w1.w*av1.w;
                    s[u] = t0 + t1;
                }
                #pragma unroll
                for (int off = 32; off > 0; off >>= 1) {
                    #pragma unroll
                    for (int u = 0; u < 8; ++u) s[u] += __shfl_xor(s[u], off);
                }
                if (lane == 0) {
                    #pragma unroll
                    for (int u = 0; u < 8; ++u) h2[nb + u] = lrelu(s[u] + b2[nb + u]);
                }
            }
        }
        __syncthreads();

        if (wv < 4) {
            const float4 w = ((const float4*)(W3 + wv * 256))[lane];
            const float4 a = ((const float4*)h2)[lane];
            float s = w.x*a.x + w.y*a.y + w.z*a.z + w.w*a.w;
            for (int off = 32; off > 0; off >>= 1) s += __shfl_xor(s, off);
            if (lane == 0) out[row * 4 + wv] = s + b3[wv];
        }
    }
}

extern "C" void kernel_launch(void* const* d_in, const int* in_sizes, int n_in,
                              void* d_out, int out_size, void* d_ws, size_t ws_size,
                              hipStream_t stream)
{
    const float* x  = (const float*)d_in[0];
    const float* W1 = (const float*)d_in[1];
    const float* b1 = (const float*)d_in[2];
    const float* W2 = (const float*)d_in[3];
    const float* b2 = (const float*)d_in[4];
    const float* W3 = (const float*)d_in[5];
    const float* b3 = (const float*)d_in[6];
    float* outp = (float*)d_out;
    float* wsn  = (float*)d_ws;                  // [0, 1MB): normalized features
    float* h1g  = wsn + 256 * 1024;              // [1MB, 1.5MB): h1 activations

    void* kargs[] = {
        (void*)&x, (void*)&W1, (void*)&b1, (void*)&W2, (void*)&b2,
        (void*)&W3, (void*)&b3, (void*)&wsn, (void*)&h1g, (void*)&outp
    };
    hipLaunchCooperativeKernel((const void*)fused_kernel, dim3(256), dim3(1024),
                               kargs, 0, stream);
}

// Round 10
// 52.611 us; speedup vs baseline: 5.0900x; 5.0900x over previous
//
#include <hip/hip_runtime.h>

typedef __attribute__((ext_vector_type(8))) short bf16x8;
typedef __attribute__((ext_vector_type(16))) float f32x16;

#define LN 8192
#define SA_ROWB 4240          // bytes/shifted-copy row; 4240/16=265 ≡ 1 (mod 8) → bank spread
#define SB_OFF  33920         // B buffer starts after 8 A-rows (8*4240)
#define SMEM_BYTES 65536

__device__ __forceinline__ unsigned short f2bf(float f) {
    unsigned int u = __float_as_uint(f);
    u += 0x7fffu + ((u >> 16) & 1u);
    return (unsigned short)(u >> 16);
}
__device__ __forceinline__ float lrelu(float v) { return v > 0.f ? v : 0.01f * v; }
__device__ __forceinline__ float gldx(const float* p, int i) { return (i >= 0 && i < LN) ? p[i] : 0.f; }

// K1: ACF via 32x32x16 bf16 MFMA, A shared across tile pair (T1=p, T2=7-p).
// Round-10: per-chunk equal re-slicing — each chunk's (pair) work is split
// evenly among the pair's 4 waves (D,S per (pair,chunk) ∈ {0,64,128}, so
// quarter-slices are multiples of 16 mq). Kills barrier-segmented imbalance.
__global__ __launch_bounds__(1024)
void acf_kernel(const float* __restrict__ x, float* __restrict__ ws)
{
    __shared__ __align__(16) unsigned char smem[SMEM_BYTES];
    __shared__ float red[16];

    const int tid  = threadIdx.x;
    const int row  = blockIdx.x;
    const int lane = tid & 63;
    const int wv   = tid >> 6;
    const float* xr = x + (size_t)row * LN;

    // lane constants (identical to round 8)
    const int jj = lane & 31;
    const int gp = lane >> 5;
    const int dd = lane & 7;
    const int hh = (lane >> 3) & 3;
    const int aoff_lane = dd * SA_ROWB + 64 + 16 * gp - 16 * hh;

    // wave job: pair p, quarter q (per-chunk slicing below)
    const int q  = wv & 3;
    const int p  = wv >> 2;
    const int T1 = p;
    const int T2 = 7 - p;
    const int s1 = 512 - 64 * p;     // T1 mq-count
    const int s2 = 64 + 64 * p;      // T2 mq-count (dual region = [0, s2))

    // ---- stage B: padded bf16 v (9248 elems), 16B-slot XOR swizzle s^((s>>3)&7) ----
    for (int s = tid; s < 1156; s += 1024) {
        const int e0 = s * 8;
        float4 fa, fb;
        if (e0 + 7 < LN) {
            fa = *(const float4*)(xr + e0);
            fb = *(const float4*)(xr + e0 + 4);
        } else {
            fa = make_float4(gldx(xr,e0),   gldx(xr,e0+1), gldx(xr,e0+2), gldx(xr,e0+3));
            fb = make_float4(gldx(xr,e0+4), gldx(xr,e0+5), gldx(xr,e0+6), gldx(xr,e0+7));
        }
        uint4 pk;
        pk.x = (unsigned)f2bf(fa.x) | ((unsigned)f2bf(fa.y) << 16);
        pk.y = (unsigned)f2bf(fa.z) | ((unsigned)f2bf(fa.w) << 16);
        pk.z = (unsigned)f2bf(fb.x) | ((unsigned)f2bf(fb.y) << 16);
        pk.w = (unsigned)f2bf(fb.z) | ((unsigned)f2bf(fb.w) << 16);
        const int ph = s ^ ((s >> 3) & 7);
        *(uint4*)(smem + SB_OFF + ph * 16) = pk;
    }

    f32x16 acc1 = {}, acc2 = {};

    for (int ch = 0; ch < 4; ++ch) {
        const int tc = ch << 11;
        __syncthreads();
        // ---- stage A: copy_d[p4] = v[tc + p4 - 32 - d] (identical to round 8) ----
        if (tid < 528) {
            const int base = tc + 4 * tid - 40;
            float4 fa, fb, fc;
            if (base >= 0 && base + 11 < LN) {
                fa = *(const float4*)(xr + base);
                fb = *(const float4*)(xr + base + 4);
                fc = *(const float4*)(xr + base + 8);
            } else {
                fa = make_float4(gldx(xr,base),   gldx(xr,base+1), gldx(xr,base+2),  gldx(xr,base+3));
                fb = make_float4(gldx(xr,base+4), gldx(xr,base+5), gldx(xr,base+6),  gldx(xr,base+7));
                fc = make_float4(gldx(xr,base+8), gldx(xr,base+9), gldx(xr,base+10), gldx(xr,base+11));
            }
            unsigned short us[12];
            us[0]=f2bf(fa.x); us[1]=f2bf(fa.y); us[2]=f2bf(fa.z);  us[3]=f2bf(fa.w);
            us[4]=f2bf(fb.x); us[5]=f2bf(fb.y); us[6]=f2bf(fb.z);  us[7]=f2bf(fb.w);
            us[8]=f2bf(fc.x); us[9]=f2bf(fc.y); us[10]=f2bf(fc.z); us[11]=f2bf(fc.w);
            #pragma unroll
            for (int d = 0; d < 8; ++d) {
                unsigned long long pk = (unsigned long long)us[8-d]
                                      | ((unsigned long long)us[9-d]  << 16)
                                      | ((unsigned long long)us[10-d] << 32)
                                      | ((unsigned long long)us[11-d] << 48);
                *(unsigned long long*)(smem + d * SA_ROWB + 8 * tid) = pk;
            }
        }
        __syncthreads();

        const int c0 = ch * 128;
        // this chunk's dual / single region sizes for pair p
        int dD = s2 - c0; dD = dD < 0 ? 0 : (dD > 128 ? 128 : dD);          // ∈ {0,64,128}
        int sLo = c0 > s2 ? c0 : s2;
        int sHi = (c0 + 128) < s1 ? (c0 + 128) : s1;
        int sS = sHi - sLo; if (sS < 0) sS = 0;                              // ∈ {0,64,128}
        // wave q's equal quarter of each region (counts are multiples of 16)
        const int wd0 = c0 + q * (dD >> 2),  wd1 = c0 + (q + 1) * (dD >> 2);
        const int ws0 = sLo + q * (sS >> 2), ws1 = sLo + (q + 1) * (sS >> 2);

        // dual: A shared between both tiles (counts mult-of-16 -> exact unroll 4)
        {
            const unsigned char* ap = smem + aoff_lane + 32 * (wd0 - c0);
            int S1 = 128 * T1 + 2 * wd0 + 4 * jj + gp;
            int S2 = 128 * T2 + 2 * wd0 + 4 * jj + gp;
            for (int mq = wd0; mq < wd1; mq += 4) {
                bf16x8 A[4], B1[4], B2[4];
                #pragma unroll
                for (int u = 0; u < 4; ++u) {
                    A[u] = *(const bf16x8*)(ap + 32 * u);
                    const int sa = S1 + 2 * u, sb = S2 + 2 * u;
                    B1[u] = *(const bf16x8*)(smem + SB_OFF + ((sa ^ ((sa >> 3) & 7)) << 4));
                    B2[u] = *(const bf16x8*)(smem + SB_OFF + ((sb ^ ((sb >> 3) & 7)) << 4));
                }
                #pragma unroll
                for (int u = 0; u < 4; ++u) {
                    acc1 = __builtin_amdgcn_mfma_f32_32x32x16_bf16(A[u], B1[u], acc1, 0, 0, 0);
                    acc2 = __builtin_amdgcn_mfma_f32_32x32x16_bf16(A[u], B2[u], acc2, 0, 0, 0);
                }
                ap += 128; S1 += 8; S2 += 8;
            }
        }
        // single: T1 only
        {
            const unsigned char* ap = smem + aoff_lane + 32 * (ws0 - c0);
            int S1 = 128 * T1 + 2 * ws0 + 4 * jj + gp;
            for (int mq = ws0; mq < ws1; mq += 4) {
                bf16x8 A[4], B1[4];
                #pragma unroll
                for (int u = 0; u < 4; ++u) {
                    A[u] = *(const bf16x8*)(ap + 32 * u);
                    const int sa = S1 + 2 * u;
                    B1[u] = *(const bf16x8*)(smem + SB_OFF + ((sa ^ ((sa >> 3) & 7)) << 4));
                }
                #pragma unroll
                for (int u = 0; u < 4; ++u)
                    acc1 = __builtin_amdgcn_mfma_f32_32x32x16_bf16(A[u], B1[u], acc1, 0, 0, 0);
                ap += 128; S1 += 8;
            }
        }
    }

    __syncthreads();   // all MFMA reads done; overlay staging with partial buffer

    // partial buffer: [T][s][j(32)][i(32 f32, 16B-blocks XOR-swizzled by j&7)] (identical)
    auto pwrite = [&](int T, int s, const f32x16& acc, bool add) {
        unsigned char* bp = smem + (T * 2 + s) * 4096 + jj * 128;
        #pragma unroll
        for (int rq = 0; rq < 4; ++rq) {
            const int bi = (2 * rq + gp) ^ (jj & 7);
            float4 w = make_float4(acc[4*rq], acc[4*rq+1], acc[4*rq+2], acc[4*rq+3]);
            float4* pp = (float4*)(bp + bi * 16);
            if (add) { float4 o = *pp; w.x += o.x; w.y += o.y; w.z += o.z; w.w += o.w; }
            *pp = w;
        }
    };
    if (q < 2) { pwrite(T1, q, acc1, false); pwrite(T2, q, acc2, false); }
    __syncthreads();
    if (q >= 2) { pwrite(T1, q - 2, acc1, true); pwrite(T2, q - 2, acc2, true); }
    __syncthreads();

    // ---- phase C: sum 2 slots, pool8, rowmax, normalize (identical) ----
    {
        const int T  = tid >> 7;
        const int j2 = (tid >> 2) & 31;
        const int rq = tid & 3;
        const unsigned char* b0 = smem + (T * 2) * 4096 + j2 * 128;
        const int biA = (2 * rq)     ^ (j2 & 7);
        const int biB = (2 * rq + 1) ^ (j2 & 7);
        float4 s0a = *(const float4*)(b0 + biA * 16);
        float4 s0b = *(const float4*)(b0 + biB * 16);
        float4 s1a = *(const float4*)(b0 + 4096 + biA * 16);
        float4 s1b = *(const float4*)(b0 + 4096 + biB * 16);
        float v0 = s0a.x + s1a.x, v1 = s0a.y + s1a.y, v2 = s0a.z + s1a.z, v3 = s0a.w + s1a.w;
        float v4 = s0b.x + s1b.x, v5 = s0b.y + s1b.y, v6 = s0b.z + s1b.z, v7 = s0b.w + s1b.w;
        float m = fmaxf(fmaxf(fmaxf(v0, v1), fmaxf(v2, v3)), fmaxf(fmaxf(v4, v5), fmaxf(v6, v7)));

        float mx = m;
        for (int off = 32; off > 0; off >>= 1) mx = fmaxf(mx, __shfl_xor(mx, off));
        if (lane == 0) red[wv] = mx;
        __syncthreads();
        float pmax = red[0];
        #pragma unroll
        for (int k = 1; k < 16; ++k) pmax = fmaxf(pmax, red[k]);
        ws[(size_t)row * 1024 + tid] = m * (1.0f / pmax);
    }
}

// K2a: layer 1 neuron-tiled GEMM (round-8 verified, unchanged)
__global__ __launch_bounds__(512)
void mlp1_kernel(const float* __restrict__ ws, const float* __restrict__ W1,
                 const float* __restrict__ b1, float* __restrict__ h1g)
{
    __shared__ __align__(16) float arow[8 * 1024];
    const int tid  = threadIdx.x;
    const int lane = tid & 63;
    const int wv   = tid >> 6;
    const int bn   = blockIdx.x & 7;
    const int rb   = blockIdx.x >> 3;

    const float4* src = (const float4*)(ws + (size_t)rb * 8192);
    float4* a4 = (float4*)arow;
    for (int i = tid; i < 2048; i += 512) a4[i] = src[i];
    __syncthreads();

    const int n0 = bn * 64 + wv * 8;
    float acc[8][8];
    #pragma unroll
    for (int u = 0; u < 8; ++u)
        #pragma unroll
        for (int r = 0; r < 8; ++r) acc[u][r] = 0.f;

    #pragma unroll
    for (int qq = 0; qq < 4; ++qq) {
        const int kq = lane + 64 * qq;
        float4 av[8];
        #pragma unroll
        for (int r = 0; r < 8; ++r) av[r] = a4[r * 256 + kq];
        #pragma unroll
        for (int u = 0; u < 8; ++u) {
            float4 w = ((const float4*)(W1 + (size_t)(n0 + u) * 1024))[kq];
            #pragma unroll
            for (int r = 0; r < 8; ++r)
                acc[u][r] += w.x*av[r].x + w.y*av[r].y + w.z*av[r].z + w.w*av[r].w;
        }
    }
    #pragma unroll
    for (int off = 32; off > 0; off >>= 1)
        #pragma unroll
        for (int u = 0; u < 8; ++u)
            #pragma unroll
            for (int r = 0; r < 8; ++r) acc[u][r] += __shfl_xor(acc[u][r], off);

    if (lane == 0) {
        #pragma unroll
        for (int u = 0; u < 8; ++u) {
            const float bb = b1[n0 + u];
            #pragma unroll
            for (int r = 0; r < 8; ++r)
                h1g[(size_t)(rb * 8 + r) * 512 + n0 + u] = lrelu(acc[u][r] + bb);
        }
    }
}

// K2b: layers 2+3 row-per-block (round-8 verified, unchanged)
__global__ __launch_bounds__(512)
void mlp23_kernel(const float* __restrict__ h1g,
                  const float* __restrict__ W2, const float* __restrict__ b2,
                  const float* __restrict__ W3, const float* __restrict__ b3,
                  float* __restrict__ out)
{
    __shared__ __align__(16) float h1s[512];
    __shared__ __align__(16) float h2[256];
    const int tid  = threadIdx.x;
    const int lane = tid & 63;
    const int wv   = tid >> 6;
    const int row  = blockIdx.x;

    if (tid < 128) ((float4*)h1s)[tid] = ((const float4*)(h1g + (size_t)row * 512))[tid];
    __syncthreads();

    {
        const float4* a4 = (const float4*)h1s;
        float4 av0 = a4[lane], av1 = a4[lane + 64];
        for (int n0 = 0; n0 < 32; n0 += 8) {
            const int nb = wv * 32 + n0;
            float s[8];
            #pragma unroll
            for (int u = 0; u < 8; ++u) {
                const float4* wr = (const float4*)(W2 + (size_t)(nb + u) * 512);
                float4 w0 = wr[lane], w1 = wr[lane + 64];
                float t0 = w0.x*av0.x + w0.y*av0.y + w0.z*av0.z + w0.w*av0.w;
                float t1 = w1.x*av1.x + w1.y*av1.y + w1.z*av1.z + w1.w*av1.w;
                s[u] = t0 + t1;
            }
            #pragma unroll
            for (int off = 32; off > 0; off >>= 1) {
                #pragma unroll
                for (int u = 0; u < 8; ++u) s[u] += __shfl_xor(s[u], off);
            }
            if (lane == 0) {
                #pragma unroll
                for (int u = 0; u < 8; ++u) h2[nb + u] = lrelu(s[u] + b2[nb + u]);
            }
        }
    }
    __syncthreads();

    if (wv < 4) {
        const float4 w = ((const float4*)(W3 + wv * 256))[lane];
        const float4 a = ((const float4*)h2)[lane];
        float s = w.x*a.x + w.y*a.y + w.z*a.z + w.w*a.w;
        for (int off = 32; off > 0; off >>= 1) s += __shfl_xor(s, off);
        if (lane == 0) out[row * 4 + wv] = s + b3[wv];
    }
}

extern "C" void kernel_launch(void* const* d_in, const int* in_sizes, int n_in,
                              void* d_out, int out_size, void* d_ws, size_t ws_size,
                              hipStream_t stream)
{
    const float* x  = (const float*)d_in[0];
    const float* W1 = (const float*)d_in[1];
    const float* b1 = (const float*)d_in[2];
    const float* W2 = (const float*)d_in[3];
    const float* b2 = (const float*)d_in[4];
    const float* W3 = (const float*)d_in[5];
    const float* b3 = (const float*)d_in[6];
    float* outp = (float*)d_out;
    float* wsn  = (float*)d_ws;                  // [0, 1MB): normalized features
    float* h1g  = wsn + 256 * 1024;              // [1MB, 1.5MB): h1 activations

    hipLaunchKernelGGL(acf_kernel,   dim3(256), dim3(1024), 0, stream, x, wsn);
    hipLaunchKernelGGL(mlp1_kernel,  dim3(256), dim3(512),  0, stream, wsn, W1, b1, h1g);
    hipLaunchKernelGGL(mlp23_kernel, dim3(256), dim3(512),  0, stream, h1g, W2, b2, W3, b3, outp);
}